// Round 15
// baseline (390.285 us; speedup 1.0000x reference)
//
#include <hip/hip_runtime.h>

#define NN 50000
#define NE 800000
#define D 64
#define SLICE 64                        // dst nodes per slice block
#define NBLK 782                        // ceil(NN/SLICE)
#define NSHARD 8                        // shards per bucket = waves per slice block
#define SCAP 256                        // per-shard capacity (mean ~128, 11 sigma), mult of 64
#define CSTRIDE 16                      // cursor padding: 64 B
#define UVNODES 128                     // nodes per uv block (32 per wave)
#define UVBLK 391                       // ceil(NN/UVNODES)
#define BINBLK 782                      // ceil((NE/4)/256)
#define SCRTOT 2304                     // sorted-list capacity (max 2240 + tail)

typedef int i32x4 __attribute__((ext_vector_type(4)));
typedef float f32x4 __attribute__((ext_vector_type(4)));

__device__ __forceinline__ float b2f(unsigned short h) {
    unsigned int u = ((unsigned int)h) << 16;
    return __builtin_bit_cast(float, u);
}
__device__ __forceinline__ unsigned short f2bf(float f) {
    unsigned int u = __builtin_bit_cast(unsigned int, f);
    u = (u + 0x7fffu + ((u >> 16) & 1u)) >> 16;
    return (unsigned short)u;
}

// ---------------------------------------------------------------------------
// pre_fused (unchanged, measured ~44 us): blocks [0, UVBLK) compute u,v with
// upfront register x-prefetch; blocks [UVBLK, ..) bin edges.
// ---------------------------------------------------------------------------
__global__ __launch_bounds__(256) void pre_fused(
    const float* __restrict__ x,
    const int* __restrict__ ei,
    const float* __restrict__ W_edge,
    const float* __restrict__ b_edge,
    unsigned short* __restrict__ u,
    unsigned short* __restrict__ v,
    unsigned int* __restrict__ bins,
    unsigned int* __restrict__ cursor)
{
    __shared__ float Wu[D * D];        // Wtop - Wbot   (16 KB)
    __shared__ float Wv[D * D];        // Wbot          (16 KB)
    __shared__ float xs[4][D][4];      // [wave][k][node] (4 KB)

    const int tid  = threadIdx.x;
    const int lane = tid & 63;
    const int wid  = tid >> 6;

    if (blockIdx.x < UVBLK) {
        for (int i = tid; i < D * D; i += 256) {
            float wt = W_edge[i], wb = W_edge[D * D + i];
            Wu[i] = wt - wb;
            Wv[i] = wb;
        }

        float xr[8][4];
#pragma unroll
        for (int g = 0; g < 8; ++g) {
            int n0 = blockIdx.x * UVNODES + wid * 32 + g * 4;
            int n0c = (n0 <= NN - 4) ? n0 : (NN - 4);
#pragma unroll
            for (int j = 0; j < 4; ++j)
                xr[g][j] = x[(size_t)(n0c + j) * D + lane];
        }
        __syncthreads();

        const float be = b_edge[lane];
#pragma unroll 1
        for (int g = 0; g < 8; ++g) {
            const int n0 = blockIdx.x * UVNODES + wid * 32 + g * 4;
#pragma unroll
            for (int j = 0; j < 4; ++j)
                xs[wid][lane][j] = xr[g][j];
            float au0 = be, au1 = be, au2 = be, au3 = be;
            float av0 = 0.f, av1 = 0.f, av2 = 0.f, av3 = 0.f;
#pragma unroll
            for (int k = 0; k < D; ++k) {
                f32x4 x4 = *(const f32x4*)&xs[wid][k][0];   // wave-uniform
                float wu = Wu[k * D + lane];
                float wv = Wv[k * D + lane];
                au0 += x4[0] * wu;  av0 += x4[0] * wv;
                au1 += x4[1] * wu;  av1 += x4[1] * wv;
                au2 += x4[2] * wu;  av2 += x4[2] * wv;
                au3 += x4[3] * wu;  av3 += x4[3] * wv;
            }
            if (n0 < NN) {
                u[(size_t)(n0 + 0) * D + lane] = f2bf(au0);
                u[(size_t)(n0 + 1) * D + lane] = f2bf(au1);
                u[(size_t)(n0 + 2) * D + lane] = f2bf(au2);
                u[(size_t)(n0 + 3) * D + lane] = f2bf(au3);
                v[(size_t)(n0 + 0) * D + lane] = f2bf(av0);
                v[(size_t)(n0 + 1) * D + lane] = f2bf(av1);
                v[(size_t)(n0 + 2) * D + lane] = f2bf(av2);
                v[(size_t)(n0 + 3) * D + lane] = f2bf(av3);
            }
        }
    } else {
        const int bb = blockIdx.x - UVBLK;
        if (bb == 0 && tid < 64)
            v[(size_t)NN * D + tid] = 0xFF80;           // sentinel row = -inf
        const int gtid = bb * 256 + tid;
        if (gtid * 4 < NE) {
            const int e0 = gtid * 4;
            const unsigned int sh = (unsigned int)(gtid & (NSHARD - 1));
            i32x4 s4 = *(const i32x4*)(ei + e0);
            i32x4 d4 = *(const i32x4*)(ei + NE + e0);
#pragma unroll
            for (int j = 0; j < 4; ++j) {
                unsigned int se = (unsigned int)s4[j];
                unsigned int de = (unsigned int)d4[j];
                unsigned int b  = (de >> 6) * NSHARD + sh;
                unsigned int pos = atomicAdd(&cursor[b * CSTRIDE], 1u);
                if (pos < SCAP)
                    bins[(size_t)b * SCAP + pos] = (se << 6) | (de & 63u);
            }
        }
    }
}

// ---------------------------------------------------------------------------
// slice: CSR build + r12 aggregation loop (verbatim) with upfront u/x row
// preloads, and a staged-x epilogue (NO shfl chain): per k one uniform
// ds_read_b128 + one ds_read_b32 + 4 FMA.
// LDS: 16K wres + 8K xsE + 9.2K sorted + 0.8K counters = 34.8 KB.
// ---------------------------------------------------------------------------
__global__ __launch_bounds__(512) void slice_kernel(
    const float* __restrict__ x,
    const float* __restrict__ W_res,
    const float* __restrict__ b_res,
    const unsigned short* __restrict__ u,
    const unsigned short* __restrict__ v,
    const unsigned int* __restrict__ bins,
    const unsigned int* __restrict__ cursor,
    float* __restrict__ out)
{
    __shared__ float wres[D * D];      // 16 KB
    __shared__ float xsE[8][D][4];     // 8 KB epilogue x staging
    __shared__ int sorted[SCRTOT];     // 9.2 KB (src ids, CSR by row)
    __shared__ int cntL[64], ofsL[64], fillL[64];

    const int tid  = threadIdx.x;
    const int lane = tid & 63;
    const int wid  = tid >> 6;                 // 0..7
    const int base = blockIdx.x * SLICE;

    // upfront row preloads (issued before CSR phases -> latency overlapped)
    float urr[8], xrr[8];
#pragma unroll
    for (int i = 0; i < 8; ++i) {
        int n = base + wid * 8 + i;
        int nc = (n < NN) ? n : (NN - 1);
        urr[i] = b2f(u[(size_t)nc * D + lane]);
        xrr[i] = x[(size_t)nc * D + lane];
    }

    for (int i = tid; i < D * D; i += 512) wres[i] = W_res[i];
    if (tid < 64) { cntL[tid] = 0; fillL[tid] = 0; }
    __syncthreads();

    // ---- CSR build: histogram own shard (no-return ds_add) ----
    const unsigned int cidx = (unsigned int)blockIdx.x * NSHARD + wid;
    unsigned int cntS = cursor[cidx * CSTRIDE];
    if (cntS > SCAP) cntS = SCAP;
    const unsigned int* __restrict__ eb = bins + (size_t)cidx * SCAP;
    for (unsigned int i0 = lane; i0 < cntS; i0 += 64)
        atomicAdd(&cntL[eb[i0] & 63u], 1);
    __syncthreads();

    // ---- exclusive prefix scan of x4-rounded counts (wave 0) ----
    if (wid == 0) {
        int a = (cntL[lane] + 3) & ~3;
        int s = a;
#pragma unroll
        for (int off = 1; off < 64; off <<= 1) {
            int t = __shfl_up(s, off);
            if (lane >= off) s += t;
        }
        ofsL[lane] = s - a;
    }
    __syncthreads();

    // ---- scatter into CSR ----
    for (unsigned int i0 = lane; i0 < cntS; i0 += 64) {
        unsigned int e = eb[i0];
        int dl = (int)(e & 63u);
        int pos = ofsL[dl] + atomicAdd(&fillL[dl], 1);
        sorted[pos] = (int)(e >> 6);
    }
    __syncthreads();

    // ---- pad lists to x4 with sentinel (+4 tail for prefetch overread) ----
    if (tid < 64) {
        int c = cntL[tid], o = ofsL[tid];
        int a = (c + 3) & ~3;
        for (int j = c; j < a; ++j) sorted[o + j] = NN;
        if (tid == 63)
            for (int t = 0; t < 4; ++t) sorted[o + a + t] = NN;
    }
    __syncthreads();

    // ---- aggregation: r12 inner loop verbatim, results in static aggr[8] ----
    float aggr[8];
#pragma unroll
    for (int i = 0; i < 8; ++i) {
        const int r = wid * 8 + i;
        const int o = ofsL[r];
        const int a = (cntL[r] + 3) & ~3;
        float m = -__builtin_inff();
        i32x4 idx = *(const i32x4*)&sorted[o];          // uniform broadcast
#pragma unroll 2
        for (int j = 0; j < a; j += 4) {
            i32x4 nx = *(const i32x4*)&sorted[o + j + 4];  // prefetch
            float v0 = b2f(v[(size_t)idx[0] * D + lane]);
            float v1 = b2f(v[(size_t)idx[1] * D + lane]);
            float v2 = b2f(v[(size_t)idx[2] * D + lane]);
            float v3 = b2f(v[(size_t)idx[3] * D + lane]);
            m = fmaxf(m, fmaxf(fmaxf(v0, v1), fmaxf(v2, v3)));
            idx = nx;
        }
        aggr[i] = fmaxf(0.f, urr[i] + m);   // relu; empty row -> -inf -> 0
    }

    // ---- epilogue: staged-x GEMM, 2 groups of 4 rows, no shfl ----
    const float br = b_res[lane];
#pragma unroll
    for (int g = 0; g < 2; ++g) {
        const int n0 = base + wid * 8 + g * 4;
#pragma unroll
        for (int j = 0; j < 4; ++j)
            xsE[wid][lane][j] = xrr[g * 4 + j];
        float s0 = br, s1 = br, s2 = br, s3 = br;
#pragma unroll
        for (int k = 0; k < D; ++k) {
            f32x4 x4 = *(const f32x4*)&xsE[wid][k][0];   // wave-uniform
            float wr = wres[k * D + lane];
            s0 += x4[0] * wr;
            s1 += x4[1] * wr;
            s2 += x4[2] * wr;
            s3 += x4[3] * wr;
        }
        if (n0 + 0 < NN) out[(size_t)(n0 + 0) * D + lane] = aggr[g * 4 + 0] + s0;
        if (n0 + 1 < NN) out[(size_t)(n0 + 1) * D + lane] = aggr[g * 4 + 1] + s1;
        if (n0 + 2 < NN) out[(size_t)(n0 + 2) * D + lane] = aggr[g * 4 + 2] + s2;
        if (n0 + 3 < NN) out[(size_t)(n0 + 3) * D + lane] = aggr[g * 4 + 3] + s3;
    }
}

extern "C" void kernel_launch(void* const* d_in, const int* in_sizes, int n_in,
                              void* d_out, int out_size, void* d_ws, size_t ws_size,
                              hipStream_t stream) {
    const float* x      = (const float*)d_in[0];
    const int*   ei     = (const int*)d_in[1];
    const float* W_edge = (const float*)d_in[2];
    const float* b_edge = (const float*)d_in[3];
    const float* W_res  = (const float*)d_in[4];
    const float* b_res  = (const float*)d_in[5];
    float* out = (float*)d_out;

    // ws: cursor u32 (~512KB) | bins u32[NBLK*NSHARD*SCAP] (6.4MB)
    //     | u bf16[NN*D] (6.4MB) | v bf16[(NN+1)*D] (6.4MB + sentinel row)
    unsigned int*   cursor = (unsigned int*)d_ws;
    unsigned int*   bins   = (unsigned int*)((char*)d_ws + (1u << 19));
    unsigned short* uu     = (unsigned short*)((char*)d_ws + (1u << 19)
                              + (size_t)NBLK * NSHARD * SCAP * 4);
    unsigned short* vv     = uu + (size_t)NN * D;

    hipMemsetAsync(cursor, 0, NBLK * NSHARD * CSTRIDE * sizeof(unsigned int), stream);
    pre_fused<<<UVBLK + BINBLK, 256, 0, stream>>>(x, ei, W_edge, b_edge, uu, vv, bins, cursor);
    slice_kernel<<<NBLK, 512, 0, stream>>>(x, W_res, b_res, uu, vv, bins, cursor, out);
}

// Round 16
// 75.915 us; speedup vs baseline: 5.1411x; 5.1411x over previous
//
#include <hip/hip_runtime.h>

#define NN 50000
#define NE 800000
#define D 64
#define SLICE 64                        // dst nodes per slice block
#define NBLK 782                        // ceil(NN/SLICE)
#define NSHARD 8                        // shards per bucket = waves per slice block
#define SCAP 256                        // per-shard capacity (mean ~128, 11 sigma), mult of 64
#define CSTRIDE 16                      // cursor padding: 64 B
#define UVNODES 128                     // nodes per uv block (32 per wave)
#define UVBLK 391                       // ceil(NN/UVNODES)
#define BINBLK 782                      // ceil((NE/4)/256)
#define SCRTOT 2304                     // sorted-list capacity (max 2240 + tail)

typedef int i32x4 __attribute__((ext_vector_type(4)));
typedef float f32x4 __attribute__((ext_vector_type(4)));

__device__ __forceinline__ float b2f(unsigned short h) {
    unsigned int u = ((unsigned int)h) << 16;
    return __builtin_bit_cast(float, u);
}
__device__ __forceinline__ unsigned short f2bf(float f) {
    unsigned int u = __builtin_bit_cast(unsigned int, f);
    u = (u + 0x7fffu + ((u >> 16) & 1u)) >> 16;
    return (unsigned short)u;
}

// ---------------------------------------------------------------------------
// pre_fused: blocks [0, UVBLK) compute u, v AND res = bf16(x@W_res + b_res)
// (three GEMMs share one staged x4 read; per k: 3 ds_read_b32 + 12 FMA).
// Blocks [UVBLK, ..) bin edges (unchanged).
// LDS: Wu 16K + Wv 16K + Wr 16K + xs 4K = 52 KB -> 3 blocks/CU.
// ---------------------------------------------------------------------------
__global__ __launch_bounds__(256) void pre_fused(
    const float* __restrict__ x,
    const int* __restrict__ ei,
    const float* __restrict__ W_edge,
    const float* __restrict__ b_edge,
    const float* __restrict__ W_res,
    const float* __restrict__ b_res,
    unsigned short* __restrict__ u,
    unsigned short* __restrict__ v,
    unsigned short* __restrict__ res,
    unsigned int* __restrict__ bins,
    unsigned int* __restrict__ cursor)
{
    __shared__ float Wu[D * D];        // Wtop - Wbot   (16 KB)
    __shared__ float Wv[D * D];        // Wbot          (16 KB)
    __shared__ float Wr[D * D];        // W_res         (16 KB)
    __shared__ float xs[4][D][4];      // [wave][k][node] (4 KB)

    const int tid  = threadIdx.x;
    const int lane = tid & 63;
    const int wid  = tid >> 6;

    if (blockIdx.x < UVBLK) {
        for (int i = tid; i < D * D; i += 256) {
            float wt = W_edge[i], wb = W_edge[D * D + i];
            Wu[i] = wt - wb;
            Wv[i] = wb;
            Wr[i] = W_res[i];
        }

        // upfront x prefetch: 32 independent loads (clamped base, stores guarded)
        float xr[8][4];
#pragma unroll
        for (int g = 0; g < 8; ++g) {
            int n0 = blockIdx.x * UVNODES + wid * 32 + g * 4;
            int n0c = (n0 <= NN - 4) ? n0 : (NN - 4);
#pragma unroll
            for (int j = 0; j < 4; ++j)
                xr[g][j] = x[(size_t)(n0c + j) * D + lane];
        }
        __syncthreads();

        const float be = b_edge[lane];
        const float br = b_res[lane];
#pragma unroll 1
        for (int g = 0; g < 8; ++g) {
            const int n0 = blockIdx.x * UVNODES + wid * 32 + g * 4;
#pragma unroll
            for (int j = 0; j < 4; ++j)
                xs[wid][lane][j] = xr[g][j];
            float au0 = be, au1 = be, au2 = be, au3 = be;
            float av0 = 0.f, av1 = 0.f, av2 = 0.f, av3 = 0.f;
            float ar0 = br, ar1 = br, ar2 = br, ar3 = br;
#pragma unroll
            for (int k = 0; k < D; ++k) {
                f32x4 x4 = *(const f32x4*)&xs[wid][k][0];   // wave-uniform
                float wu = Wu[k * D + lane];
                float wv = Wv[k * D + lane];
                float wr = Wr[k * D + lane];
                au0 += x4[0] * wu;  av0 += x4[0] * wv;  ar0 += x4[0] * wr;
                au1 += x4[1] * wu;  av1 += x4[1] * wv;  ar1 += x4[1] * wr;
                au2 += x4[2] * wu;  av2 += x4[2] * wv;  ar2 += x4[2] * wr;
                au3 += x4[3] * wu;  av3 += x4[3] * wv;  ar3 += x4[3] * wr;
            }
            if (n0 < NN) {   // n0 % 4 == 0 and NN % 4 == 0 -> all 4 valid
                u[(size_t)(n0 + 0) * D + lane] = f2bf(au0);
                u[(size_t)(n0 + 1) * D + lane] = f2bf(au1);
                u[(size_t)(n0 + 2) * D + lane] = f2bf(au2);
                u[(size_t)(n0 + 3) * D + lane] = f2bf(au3);
                v[(size_t)(n0 + 0) * D + lane] = f2bf(av0);
                v[(size_t)(n0 + 1) * D + lane] = f2bf(av1);
                v[(size_t)(n0 + 2) * D + lane] = f2bf(av2);
                v[(size_t)(n0 + 3) * D + lane] = f2bf(av3);
                res[(size_t)(n0 + 0) * D + lane] = f2bf(ar0);
                res[(size_t)(n0 + 1) * D + lane] = f2bf(ar1);
                res[(size_t)(n0 + 2) * D + lane] = f2bf(ar2);
                res[(size_t)(n0 + 3) * D + lane] = f2bf(ar3);
            }
        }
    } else {
        const int bb = blockIdx.x - UVBLK;
        if (bb == 0 && tid < 64)
            v[(size_t)NN * D + tid] = 0xFF80;           // sentinel row = -inf
        const int gtid = bb * 256 + tid;
        if (gtid * 4 < NE) {
            const int e0 = gtid * 4;
            const unsigned int sh = (unsigned int)(gtid & (NSHARD - 1));
            i32x4 s4 = *(const i32x4*)(ei + e0);
            i32x4 d4 = *(const i32x4*)(ei + NE + e0);
#pragma unroll
            for (int j = 0; j < 4; ++j) {
                unsigned int se = (unsigned int)s4[j];
                unsigned int de = (unsigned int)d4[j];
                unsigned int b  = (de >> 6) * NSHARD + sh;
                unsigned int pos = atomicAdd(&cursor[b * CSTRIDE], 1u);
                if (pos < SCAP)
                    bins[(size_t)b * SCAP + pos] = (se << 6) | (de & 63u);
            }
        }
    }
}

// ---------------------------------------------------------------------------
// slice (r12 structure, epilogue GEMM REMOVED): CSR build + unroll-1 row loop:
//   m = register max over neighbor v-rows; out = relu(u+m) + res  (one
//   coalesced res load + add — no wres staging, no xsE, no k-loop).
// LDS: 9.2K sorted + 0.8K counters = 10 KB. VGPR ~20, no live arrays.
// ---------------------------------------------------------------------------
__global__ __launch_bounds__(512) void slice_kernel(
    const unsigned short* __restrict__ u,
    const unsigned short* __restrict__ v,
    const unsigned short* __restrict__ res,
    const unsigned int* __restrict__ bins,
    const unsigned int* __restrict__ cursor,
    float* __restrict__ out)
{
    __shared__ int sorted[SCRTOT];     // 9.2 KB (src ids, CSR by row)
    __shared__ int cntL[64], ofsL[64], fillL[64];

    const int tid  = threadIdx.x;
    const int lane = tid & 63;
    const int wid  = tid >> 6;                 // 0..7
    const int base = blockIdx.x * SLICE;

    if (tid < 64) { cntL[tid] = 0; fillL[tid] = 0; }
    __syncthreads();

    // ---- CSR build: histogram own shard (no-return ds_add) ----
    const unsigned int cidx = (unsigned int)blockIdx.x * NSHARD + wid;
    unsigned int cntS = cursor[cidx * CSTRIDE];
    if (cntS > SCAP) cntS = SCAP;
    const unsigned int* __restrict__ eb = bins + (size_t)cidx * SCAP;
    for (unsigned int i0 = lane; i0 < cntS; i0 += 64)
        atomicAdd(&cntL[eb[i0] & 63u], 1);
    __syncthreads();

    // ---- exclusive prefix scan of x4-rounded counts (wave 0) ----
    if (wid == 0) {
        int a = (cntL[lane] + 3) & ~3;
        int s = a;
#pragma unroll
        for (int off = 1; off < 64; off <<= 1) {
            int t = __shfl_up(s, off);
            if (lane >= off) s += t;
        }
        ofsL[lane] = s - a;
    }
    __syncthreads();

    // ---- scatter into CSR ----
    for (unsigned int i0 = lane; i0 < cntS; i0 += 64) {
        unsigned int e = eb[i0];
        int dl = (int)(e & 63u);
        int pos = ofsL[dl] + atomicAdd(&fillL[dl], 1);
        sorted[pos] = (int)(e >> 6);
    }
    __syncthreads();

    // ---- pad lists to x4 with sentinel (+4 tail for prefetch overread) ----
    if (tid < 64) {
        int c = cntL[tid], o = ofsL[tid];
        int a = (c + 3) & ~3;
        for (int j = c; j < a; ++j) sorted[o + j] = NN;
        if (tid == 63)
            for (int t = 0; t < 4; ++t) sorted[o + a + t] = NN;
    }
    __syncthreads();

    // ---- aggregate + trivial epilogue: 8 rows per wave, lane = column ----
#pragma unroll 1
    for (int i = 0; i < 8; ++i) {
        int r = wid * 8 + i;
        int n = base + r;
        if (n >= NN) break;
        float ur = b2f(u[(size_t)n * D + lane]);
        float rr = b2f(res[(size_t)n * D + lane]);
        const int o = ofsL[r];
        const int a = (cntL[r] + 3) & ~3;
        float m = -__builtin_inff();
        i32x4 idx = *(const i32x4*)&sorted[o];          // uniform broadcast
#pragma unroll 2
        for (int j = 0; j < a; j += 4) {
            i32x4 nx = *(const i32x4*)&sorted[o + j + 4];  // prefetch
            float v0 = b2f(v[(size_t)idx[0] * D + lane]);
            float v1 = b2f(v[(size_t)idx[1] * D + lane]);
            float v2 = b2f(v[(size_t)idx[2] * D + lane]);
            float v3 = b2f(v[(size_t)idx[3] * D + lane]);
            m = fmaxf(m, fmaxf(fmaxf(v0, v1), fmaxf(v2, v3)));
            idx = nx;
        }
        float agg = fmaxf(0.f, ur + m);   // relu; empty row -> -inf -> 0
        out[(size_t)n * D + lane] = agg + rr;
    }
}

extern "C" void kernel_launch(void* const* d_in, const int* in_sizes, int n_in,
                              void* d_out, int out_size, void* d_ws, size_t ws_size,
                              hipStream_t stream) {
    const float* x      = (const float*)d_in[0];
    const int*   ei     = (const int*)d_in[1];
    const float* W_edge = (const float*)d_in[2];
    const float* b_edge = (const float*)d_in[3];
    const float* W_res  = (const float*)d_in[4];
    const float* b_res  = (const float*)d_in[5];
    float* out = (float*)d_out;

    // ws: cursor u32 (512KB) | bins u32[NBLK*NSHARD*SCAP] (6.4MB)
    //     | u bf16 (6.4MB) | v bf16 (6.4MB + sentinel row) | res bf16 (6.4MB)
    unsigned int*   cursor = (unsigned int*)d_ws;
    unsigned int*   bins   = (unsigned int*)((char*)d_ws + (1u << 19));
    unsigned short* uu     = (unsigned short*)((char*)d_ws + (1u << 19)
                              + (size_t)NBLK * NSHARD * SCAP * 4);
    unsigned short* vv     = uu + (size_t)NN * D;
    unsigned short* rr     = vv + (size_t)(NN + 1) * D;   // after sentinel row

    hipMemsetAsync(cursor, 0, NBLK * NSHARD * CSTRIDE * sizeof(unsigned int), stream);
    pre_fused<<<UVBLK + BINBLK, 256, 0, stream>>>(x, ei, W_edge, b_edge, W_res, b_res,
                                                  uu, vv, rr, bins, cursor);
    slice_kernel<<<NBLK, 512, 0, stream>>>(uu, vv, rr, bins, cursor, out);
}

// Round 17
// 64.301 us; speedup vs baseline: 6.0696x; 1.1806x over previous
//
#include <hip/hip_runtime.h>

#define NN 50000
#define NE 800000
#define D 64
#define SLICE 64                        // dst nodes per slice block
#define NBLK 782                        // ceil(NN/SLICE) = buckets
#define BCAP 1536                       // per-bucket capacity (mean 1024, >15 sigma)
#define CSTRIDE 16                      // cursor padding: 64 B
#define UVNODES 128                     // nodes per uv block (32 per wave)
#define UVBLK 391                       // ceil(NN/UVNODES)
#define BINBLK 98                       // fat bin blocks (8192 edges each)
#define EPB 8192                        // edges per bin block
#define SCRTOT 2304                     // sorted-list capacity

typedef int i32x4 __attribute__((ext_vector_type(4)));
typedef float f32x4 __attribute__((ext_vector_type(4)));

__device__ __forceinline__ float b2f(unsigned short h) {
    unsigned int u = ((unsigned int)h) << 16;
    return __builtin_bit_cast(float, u);
}
__device__ __forceinline__ unsigned short f2bf(float f) {
    unsigned int u = __builtin_bit_cast(unsigned int, f);
    u = (u + 0x7fffu + ((u >> 16) & 1u)) >> 16;
    return (unsigned short)u;
}

// ---------------------------------------------------------------------------
// pre_fused: blocks [0, UVBLK) = uv/res GEMMs (unchanged from r16).
// Blocks [UVBLK, UVBLK+BINBLK) = histogram binning, 8192 edges each:
//   A: LDS histogram (ds atomics)     -> hist[782]   (aliases Wu)
//   B: ONE global atomicAdd per touched bucket (~570) -> base[782] (aliases Wv)
//   C: re-read edges (L1/L2 hot), pos = base + LDS fill, store entry.
// Global atomics: 800K -> ~56K total.
// ---------------------------------------------------------------------------
__global__ __launch_bounds__(256) void pre_fused(
    const float* __restrict__ x,
    const int* __restrict__ ei,
    const float* __restrict__ W_edge,
    const float* __restrict__ b_edge,
    const float* __restrict__ W_res,
    const float* __restrict__ b_res,
    unsigned short* __restrict__ u,
    unsigned short* __restrict__ v,
    unsigned short* __restrict__ res,
    unsigned int* __restrict__ bins,
    unsigned int* __restrict__ cursor)
{
    __shared__ float Wu[D * D];        // Wtop - Wbot   (16 KB)  | bin: hist/fill
    __shared__ float Wv[D * D];        // Wbot          (16 KB)  | bin: base
    __shared__ float Wr[D * D];        // W_res         (16 KB)
    __shared__ float xs[4][D][4];      // [wave][k][node] (4 KB)

    const int tid  = threadIdx.x;
    const int lane = tid & 63;
    const int wid  = tid >> 6;

    if (blockIdx.x < UVBLK) {
        for (int i = tid; i < D * D; i += 256) {
            float wt = W_edge[i], wb = W_edge[D * D + i];
            Wu[i] = wt - wb;
            Wv[i] = wb;
            Wr[i] = W_res[i];
        }

        float xr[8][4];
#pragma unroll
        for (int g = 0; g < 8; ++g) {
            int n0 = blockIdx.x * UVNODES + wid * 32 + g * 4;
            int n0c = (n0 <= NN - 4) ? n0 : (NN - 4);
#pragma unroll
            for (int j = 0; j < 4; ++j)
                xr[g][j] = x[(size_t)(n0c + j) * D + lane];
        }
        __syncthreads();

        const float be = b_edge[lane];
        const float br = b_res[lane];
#pragma unroll 1
        for (int g = 0; g < 8; ++g) {
            const int n0 = blockIdx.x * UVNODES + wid * 32 + g * 4;
#pragma unroll
            for (int j = 0; j < 4; ++j)
                xs[wid][lane][j] = xr[g][j];
            float au0 = be, au1 = be, au2 = be, au3 = be;
            float av0 = 0.f, av1 = 0.f, av2 = 0.f, av3 = 0.f;
            float ar0 = br, ar1 = br, ar2 = br, ar3 = br;
#pragma unroll
            for (int k = 0; k < D; ++k) {
                f32x4 x4 = *(const f32x4*)&xs[wid][k][0];   // wave-uniform
                float wu = Wu[k * D + lane];
                float wv = Wv[k * D + lane];
                float wr = Wr[k * D + lane];
                au0 += x4[0] * wu;  av0 += x4[0] * wv;  ar0 += x4[0] * wr;
                au1 += x4[1] * wu;  av1 += x4[1] * wv;  ar1 += x4[1] * wr;
                au2 += x4[2] * wu;  av2 += x4[2] * wv;  ar2 += x4[2] * wr;
                au3 += x4[3] * wu;  av3 += x4[3] * wv;  ar3 += x4[3] * wr;
            }
            if (n0 < NN) {
                u[(size_t)(n0 + 0) * D + lane] = f2bf(au0);
                u[(size_t)(n0 + 1) * D + lane] = f2bf(au1);
                u[(size_t)(n0 + 2) * D + lane] = f2bf(au2);
                u[(size_t)(n0 + 3) * D + lane] = f2bf(au3);
                v[(size_t)(n0 + 0) * D + lane] = f2bf(av0);
                v[(size_t)(n0 + 1) * D + lane] = f2bf(av1);
                v[(size_t)(n0 + 2) * D + lane] = f2bf(av2);
                v[(size_t)(n0 + 3) * D + lane] = f2bf(av3);
                res[(size_t)(n0 + 0) * D + lane] = f2bf(ar0);
                res[(size_t)(n0 + 1) * D + lane] = f2bf(ar1);
                res[(size_t)(n0 + 2) * D + lane] = f2bf(ar2);
                res[(size_t)(n0 + 3) * D + lane] = f2bf(ar3);
            }
        }
    } else {
        // ---- histogram binning ----
        const int bb = blockIdx.x - UVBLK;
        if (bb == 0 && tid < 64)
            v[(size_t)NN * D + tid] = 0xFF80;           // sentinel row = -inf
        int* hist  = (int*)Wu;            // [NBLK]
        int* fillb = (int*)Wu + 1024;     // [NBLK]
        int* baseb = (int*)Wv;            // [NBLK]
        for (int i = tid; i < NBLK; i += 256) { hist[i] = 0; fillb[i] = 0; }
        __syncthreads();

        // phase A: LDS histogram (8 x int4 per thread, strided chunks)
#pragma unroll 1
        for (int t = 0; t < 8; ++t) {
            int e = bb * EPB + t * 1024 + tid * 4;
            if (e < NE) {
                i32x4 d4 = *(const i32x4*)(ei + NE + e);
#pragma unroll
                for (int j = 0; j < 4; ++j)
                    atomicAdd(&hist[((unsigned int)d4[j]) >> 6], 1);
            }
        }
        __syncthreads();

        // phase B: one global atomicAdd per touched bucket
        for (int b = tid; b < NBLK; b += 256) {
            int h = hist[b];
            baseb[b] = h ? (int)atomicAdd(&cursor[b * CSTRIDE], (unsigned)h) : 0;
        }
        __syncthreads();

        // phase C: place edges (re-read, L1/L2 hot)
#pragma unroll 1
        for (int t = 0; t < 8; ++t) {
            int e = bb * EPB + t * 1024 + tid * 4;
            if (e < NE) {
                i32x4 s4 = *(const i32x4*)(ei + e);
                i32x4 d4 = *(const i32x4*)(ei + NE + e);
#pragma unroll
                for (int j = 0; j < 4; ++j) {
                    unsigned int de = (unsigned int)d4[j];
                    unsigned int b  = de >> 6;
                    int pos = baseb[b] + atomicAdd(&fillb[b], 1);
                    if (pos < BCAP)
                        bins[(size_t)b * BCAP + pos] =
                            (((unsigned int)s4[j]) << 6) | (de & 63u);
                }
            }
        }
    }
}

// ---------------------------------------------------------------------------
// slice (r16 structure; shard loop replaced by single bucket list):
// CSR build (all 512 threads) + unroll-1 row loop:
//   m = register max over neighbor v-rows; out = relu(u+m) + res.
// LDS: 9.2K sorted + 0.8K counters = 10 KB. VGPR ~20.
// ---------------------------------------------------------------------------
__global__ __launch_bounds__(512) void slice_kernel(
    const unsigned short* __restrict__ u,
    const unsigned short* __restrict__ v,
    const unsigned short* __restrict__ res,
    const unsigned int* __restrict__ bins,
    const unsigned int* __restrict__ cursor,
    float* __restrict__ out)
{
    __shared__ int sorted[SCRTOT];     // src ids, CSR by row
    __shared__ int cntL[64], ofsL[64], fillL[64];

    const int tid  = threadIdx.x;
    const int lane = tid & 63;
    const int wid  = tid >> 6;                 // 0..7
    const int base = blockIdx.x * SLICE;

    if (tid < 64) { cntL[tid] = 0; fillL[tid] = 0; }
    __syncthreads();

    unsigned int cnt = cursor[blockIdx.x * CSTRIDE];
    if (cnt > BCAP) cnt = BCAP;
    const unsigned int* __restrict__ eb = bins + (size_t)blockIdx.x * BCAP;

    // ---- histogram by dst row (all threads) ----
    for (unsigned int i0 = tid; i0 < cnt; i0 += 512)
        atomicAdd(&cntL[eb[i0] & 63u], 1);
    __syncthreads();

    // ---- exclusive prefix scan of x4-rounded counts (wave 0) ----
    if (wid == 0) {
        int a = (cntL[lane] + 3) & ~3;
        int s = a;
#pragma unroll
        for (int off = 1; off < 64; off <<= 1) {
            int t = __shfl_up(s, off);
            if (lane >= off) s += t;
        }
        ofsL[lane] = s - a;
    }
    __syncthreads();

    // ---- scatter into CSR ----
    for (unsigned int i0 = tid; i0 < cnt; i0 += 512) {
        unsigned int e = eb[i0];
        int dl = (int)(e & 63u);
        int pos = ofsL[dl] + atomicAdd(&fillL[dl], 1);
        sorted[pos] = (int)(e >> 6);
    }
    __syncthreads();

    // ---- pad lists to x4 with sentinel (+4 tail for prefetch overread) ----
    if (tid < 64) {
        int c = cntL[tid], o = ofsL[tid];
        int a = (c + 3) & ~3;
        for (int j = c; j < a; ++j) sorted[o + j] = NN;
        if (tid == 63)
            for (int t = 0; t < 4; ++t) sorted[o + a + t] = NN;
    }
    __syncthreads();

    // ---- aggregate + trivial epilogue: 8 rows per wave, lane = column ----
#pragma unroll 1
    for (int i = 0; i < 8; ++i) {
        int r = wid * 8 + i;
        int n = base + r;
        if (n >= NN) break;
        float ur = b2f(u[(size_t)n * D + lane]);
        float rr = b2f(res[(size_t)n * D + lane]);
        const int o = ofsL[r];
        const int a = (cntL[r] + 3) & ~3;
        float m = -__builtin_inff();
        i32x4 idx = *(const i32x4*)&sorted[o];          // uniform broadcast
#pragma unroll 2
        for (int j = 0; j < a; j += 4) {
            i32x4 nx = *(const i32x4*)&sorted[o + j + 4];  // prefetch
            float v0 = b2f(v[(size_t)idx[0] * D + lane]);
            float v1 = b2f(v[(size_t)idx[1] * D + lane]);
            float v2 = b2f(v[(size_t)idx[2] * D + lane]);
            float v3 = b2f(v[(size_t)idx[3] * D + lane]);
            m = fmaxf(m, fmaxf(fmaxf(v0, v1), fmaxf(v2, v3)));
            idx = nx;
        }
        float agg = fmaxf(0.f, ur + m);   // relu; empty row -> -inf -> 0
        out[(size_t)n * D + lane] = agg + rr;
    }
}

extern "C" void kernel_launch(void* const* d_in, const int* in_sizes, int n_in,
                              void* d_out, int out_size, void* d_ws, size_t ws_size,
                              hipStream_t stream) {
    const float* x      = (const float*)d_in[0];
    const int*   ei     = (const int*)d_in[1];
    const float* W_edge = (const float*)d_in[2];
    const float* b_edge = (const float*)d_in[3];
    const float* W_res  = (const float*)d_in[4];
    const float* b_res  = (const float*)d_in[5];
    float* out = (float*)d_out;

    // ws: cursor u32[NBLK*CSTRIDE] (reserve 512KB) | bins u32[NBLK*BCAP] (4.8MB)
    //     | u bf16 (6.4MB) | v bf16 (6.4MB + sentinel row) | res bf16 (6.4MB)
    unsigned int*   cursor = (unsigned int*)d_ws;
    unsigned int*   bins   = (unsigned int*)((char*)d_ws + (1u << 19));
    unsigned short* uu     = (unsigned short*)((char*)d_ws + (1u << 19)
                              + (size_t)NBLK * BCAP * 4);
    unsigned short* vv     = uu + (size_t)NN * D;
    unsigned short* rr     = vv + (size_t)(NN + 1) * D;   // after sentinel row

    hipMemsetAsync(cursor, 0, NBLK * CSTRIDE * sizeof(unsigned int), stream);
    pre_fused<<<UVBLK + BINBLK, 256, 0, stream>>>(x, ei, W_edge, b_edge, W_res, b_res,
                                                  uu, vv, rr, bins, cursor);
    slice_kernel<<<NBLK, 512, 0, stream>>>(uu, vv, rr, bins, cursor, out);
}

// Round 18
// 64.175 us; speedup vs baseline: 6.0816x; 1.0020x over previous
//
#include <hip/hip_runtime.h>

#define NN 50000
#define NE 800000
#define D 64
#define SLICE 64                        // dst nodes per slice block
#define NBLK 782                        // ceil(NN/SLICE) = buckets
#define BCAP 1536                       // per-bucket capacity (mean 1024, >15 sigma)
#define CSTRIDE 4                       // cursor padding: 16 B
#define UVNODES 128                     // nodes per uv block (32 per wave)
#define UVBLK 391                       // ceil(NN/UVNODES)
#define BINBLK 98                       // fat bin blocks (8192 edges each)
#define EPB 8192                        // edges per bin block
#define SCRTOT 2304                     // sorted-list capacity
#define CURWORDS (NBLK * CSTRIDE)       // 3128 dwords

typedef int i32x4 __attribute__((ext_vector_type(4)));
typedef float f32x4 __attribute__((ext_vector_type(4)));

__device__ __forceinline__ float b2f(unsigned short h) {
    unsigned int u = ((unsigned int)h) << 16;
    return __builtin_bit_cast(float, u);
}
__device__ __forceinline__ unsigned short f2bf(float f) {
    unsigned int u = __builtin_bit_cast(unsigned int, f);
    u = (u + 0x7fffu + ((u >> 16) & 1u)) >> 16;
    return (unsigned short)u;
}

// ---------------------------------------------------------------------------
// zero_cursor: replaces hipMemsetAsync (rocclr fill took 43 us for 50 KB!)
// ---------------------------------------------------------------------------
__global__ __launch_bounds__(256) void zero_cursor(unsigned int* __restrict__ cursor)
{
    int i = blockIdx.x * 256 + threadIdx.x;
    if (i < CURWORDS) cursor[i] = 0u;
}

// ---------------------------------------------------------------------------
// pre_fused: blocks [0, UVBLK) = uv/res GEMMs; blocks [UVBLK, ..) = histogram
// binning (LDS hist -> one global atomicAdd per touched bucket -> place).
// ---------------------------------------------------------------------------
__global__ __launch_bounds__(256) void pre_fused(
    const float* __restrict__ x,
    const int* __restrict__ ei,
    const float* __restrict__ W_edge,
    const float* __restrict__ b_edge,
    const float* __restrict__ W_res,
    const float* __restrict__ b_res,
    unsigned short* __restrict__ u,
    unsigned short* __restrict__ v,
    unsigned short* __restrict__ res,
    unsigned int* __restrict__ bins,
    unsigned int* __restrict__ cursor)
{
    __shared__ float Wu[D * D];        // Wtop - Wbot   (16 KB)  | bin: hist/fill
    __shared__ float Wv[D * D];        // Wbot          (16 KB)  | bin: base
    __shared__ float Wr[D * D];        // W_res         (16 KB)
    __shared__ float xs[4][D][4];      // [wave][k][node] (4 KB)

    const int tid  = threadIdx.x;
    const int lane = tid & 63;
    const int wid  = tid >> 6;

    if (blockIdx.x < UVBLK) {
        for (int i = tid; i < D * D; i += 256) {
            float wt = W_edge[i], wb = W_edge[D * D + i];
            Wu[i] = wt - wb;
            Wv[i] = wb;
            Wr[i] = W_res[i];
        }

        float xr[8][4];
#pragma unroll
        for (int g = 0; g < 8; ++g) {
            int n0 = blockIdx.x * UVNODES + wid * 32 + g * 4;
            int n0c = (n0 <= NN - 4) ? n0 : (NN - 4);
#pragma unroll
            for (int j = 0; j < 4; ++j)
                xr[g][j] = x[(size_t)(n0c + j) * D + lane];
        }
        __syncthreads();

        const float be = b_edge[lane];
        const float br = b_res[lane];
#pragma unroll 1
        for (int g = 0; g < 8; ++g) {
            const int n0 = blockIdx.x * UVNODES + wid * 32 + g * 4;
#pragma unroll
            for (int j = 0; j < 4; ++j)
                xs[wid][lane][j] = xr[g][j];
            float au0 = be, au1 = be, au2 = be, au3 = be;
            float av0 = 0.f, av1 = 0.f, av2 = 0.f, av3 = 0.f;
            float ar0 = br, ar1 = br, ar2 = br, ar3 = br;
#pragma unroll
            for (int k = 0; k < D; ++k) {
                f32x4 x4 = *(const f32x4*)&xs[wid][k][0];   // wave-uniform
                float wu = Wu[k * D + lane];
                float wv = Wv[k * D + lane];
                float wr = Wr[k * D + lane];
                au0 += x4[0] * wu;  av0 += x4[0] * wv;  ar0 += x4[0] * wr;
                au1 += x4[1] * wu;  av1 += x4[1] * wv;  ar1 += x4[1] * wr;
                au2 += x4[2] * wu;  av2 += x4[2] * wv;  ar2 += x4[2] * wr;
                au3 += x4[3] * wu;  av3 += x4[3] * wv;  ar3 += x4[3] * wr;
            }
            if (n0 < NN) {
                u[(size_t)(n0 + 0) * D + lane] = f2bf(au0);
                u[(size_t)(n0 + 1) * D + lane] = f2bf(au1);
                u[(size_t)(n0 + 2) * D + lane] = f2bf(au2);
                u[(size_t)(n0 + 3) * D + lane] = f2bf(au3);
                v[(size_t)(n0 + 0) * D + lane] = f2bf(av0);
                v[(size_t)(n0 + 1) * D + lane] = f2bf(av1);
                v[(size_t)(n0 + 2) * D + lane] = f2bf(av2);
                v[(size_t)(n0 + 3) * D + lane] = f2bf(av3);
                res[(size_t)(n0 + 0) * D + lane] = f2bf(ar0);
                res[(size_t)(n0 + 1) * D + lane] = f2bf(ar1);
                res[(size_t)(n0 + 2) * D + lane] = f2bf(ar2);
                res[(size_t)(n0 + 3) * D + lane] = f2bf(ar3);
            }
        }
    } else {
        // ---- histogram binning ----
        const int bb = blockIdx.x - UVBLK;
        if (bb == 0 && tid < 64)
            v[(size_t)NN * D + tid] = 0xFF80;           // sentinel row = -inf
        int* hist  = (int*)Wu;            // [NBLK]
        int* fillb = (int*)Wu + 1024;     // [NBLK]
        int* baseb = (int*)Wv;            // [NBLK]
        for (int i = tid; i < NBLK; i += 256) { hist[i] = 0; fillb[i] = 0; }
        __syncthreads();

        // phase A: LDS histogram (8 x int4 per thread, strided chunks)
#pragma unroll 1
        for (int t = 0; t < 8; ++t) {
            int e = bb * EPB + t * 1024 + tid * 4;
            if (e < NE) {
                i32x4 d4 = *(const i32x4*)(ei + NE + e);
#pragma unroll
                for (int j = 0; j < 4; ++j)
                    atomicAdd(&hist[((unsigned int)d4[j]) >> 6], 1);
            }
        }
        __syncthreads();

        // phase B: one global atomicAdd per touched bucket
        for (int b = tid; b < NBLK; b += 256) {
            int h = hist[b];
            baseb[b] = h ? (int)atomicAdd(&cursor[b * CSTRIDE], (unsigned)h) : 0;
        }
        __syncthreads();

        // phase C: place edges (re-read, L1/L2 hot)
#pragma unroll 1
        for (int t = 0; t < 8; ++t) {
            int e = bb * EPB + t * 1024 + tid * 4;
            if (e < NE) {
                i32x4 s4 = *(const i32x4*)(ei + e);
                i32x4 d4 = *(const i32x4*)(ei + NE + e);
#pragma unroll
                for (int j = 0; j < 4; ++j) {
                    unsigned int de = (unsigned int)d4[j];
                    unsigned int b  = de >> 6;
                    int pos = baseb[b] + atomicAdd(&fillb[b], 1);
                    if (pos < BCAP)
                        bins[(size_t)b * BCAP + pos] =
                            (((unsigned int)s4[j]) << 6) | (de & 63u);
                }
            }
        }
    }
}

// ---------------------------------------------------------------------------
// slice: CSR build (all 512 threads) + unroll-1 row loop:
//   m = register max over neighbor v-rows; out = relu(u+m) + res.
// ---------------------------------------------------------------------------
__global__ __launch_bounds__(512) void slice_kernel(
    const unsigned short* __restrict__ u,
    const unsigned short* __restrict__ v,
    const unsigned short* __restrict__ res,
    const unsigned int* __restrict__ bins,
    const unsigned int* __restrict__ cursor,
    float* __restrict__ out)
{
    __shared__ int sorted[SCRTOT];     // src ids, CSR by row
    __shared__ int cntL[64], ofsL[64], fillL[64];

    const int tid  = threadIdx.x;
    const int lane = tid & 63;
    const int wid  = tid >> 6;                 // 0..7
    const int base = blockIdx.x * SLICE;

    if (tid < 64) { cntL[tid] = 0; fillL[tid] = 0; }
    __syncthreads();

    unsigned int cnt = cursor[blockIdx.x * CSTRIDE];
    if (cnt > BCAP) cnt = BCAP;
    const unsigned int* __restrict__ eb = bins + (size_t)blockIdx.x * BCAP;

    // ---- histogram by dst row (all threads) ----
    for (unsigned int i0 = tid; i0 < cnt; i0 += 512)
        atomicAdd(&cntL[eb[i0] & 63u], 1);
    __syncthreads();

    // ---- exclusive prefix scan of x4-rounded counts (wave 0) ----
    if (wid == 0) {
        int a = (cntL[lane] + 3) & ~3;
        int s = a;
#pragma unroll
        for (int off = 1; off < 64; off <<= 1) {
            int t = __shfl_up(s, off);
            if (lane >= off) s += t;
        }
        ofsL[lane] = s - a;
    }
    __syncthreads();

    // ---- scatter into CSR ----
    for (unsigned int i0 = tid; i0 < cnt; i0 += 512) {
        unsigned int e = eb[i0];
        int dl = (int)(e & 63u);
        int pos = ofsL[dl] + atomicAdd(&fillL[dl], 1);
        sorted[pos] = (int)(e >> 6);
    }
    __syncthreads();

    // ---- pad lists to x4 with sentinel (+4 tail for prefetch overread) ----
    if (tid < 64) {
        int c = cntL[tid], o = ofsL[tid];
        int a = (c + 3) & ~3;
        for (int j = c; j < a; ++j) sorted[o + j] = NN;
        if (tid == 63)
            for (int t = 0; t < 4; ++t) sorted[o + a + t] = NN;
    }
    __syncthreads();

    // ---- aggregate + trivial epilogue: 8 rows per wave, lane = column ----
#pragma unroll 1
    for (int i = 0; i < 8; ++i) {
        int r = wid * 8 + i;
        int n = base + r;
        if (n >= NN) break;
        float ur = b2f(u[(size_t)n * D + lane]);
        float rr = b2f(res[(size_t)n * D + lane]);
        const int o = ofsL[r];
        const int a = (cntL[r] + 3) & ~3;
        float m = -__builtin_inff();
        i32x4 idx = *(const i32x4*)&sorted[o];          // uniform broadcast
#pragma unroll 2
        for (int j = 0; j < a; j += 4) {
            i32x4 nx = *(const i32x4*)&sorted[o + j + 4];  // prefetch
            float v0 = b2f(v[(size_t)idx[0] * D + lane]);
            float v1 = b2f(v[(size_t)idx[1] * D + lane]);
            float v2 = b2f(v[(size_t)idx[2] * D + lane]);
            float v3 = b2f(v[(size_t)idx[3] * D + lane]);
            m = fmaxf(m, fmaxf(fmaxf(v0, v1), fmaxf(v2, v3)));
            idx = nx;
        }
        float agg = fmaxf(0.f, ur + m);   // relu; empty row -> -inf -> 0
        out[(size_t)n * D + lane] = agg + rr;
    }
}

extern "C" void kernel_launch(void* const* d_in, const int* in_sizes, int n_in,
                              void* d_out, int out_size, void* d_ws, size_t ws_size,
                              hipStream_t stream) {
    const float* x      = (const float*)d_in[0];
    const int*   ei     = (const int*)d_in[1];
    const float* W_edge = (const float*)d_in[2];
    const float* b_edge = (const float*)d_in[3];
    const float* W_res  = (const float*)d_in[4];
    const float* b_res  = (const float*)d_in[5];
    float* out = (float*)d_out;

    // ws: cursor u32[CURWORDS] (reserve 64KB) | bins u32[NBLK*BCAP] (4.8MB)
    //     | u bf16 (6.4MB) | v bf16 (6.4MB + sentinel row) | res bf16 (6.4MB)
    unsigned int*   cursor = (unsigned int*)d_ws;
    unsigned int*   bins   = (unsigned int*)((char*)d_ws + (1u << 16));
    unsigned short* uu     = (unsigned short*)((char*)d_ws + (1u << 16)
                              + (size_t)NBLK * BCAP * 4);
    unsigned short* vv     = uu + (size_t)NN * D;
    unsigned short* rr     = vv + (size_t)(NN + 1) * D;   // after sentinel row

    zero_cursor<<<(CURWORDS + 255) / 256, 256, 0, stream>>>(cursor);
    pre_fused<<<UVBLK + BINBLK, 256, 0, stream>>>(x, ei, W_edge, b_edge, W_res, b_res,
                                                  uu, vv, rr, bins, cursor);
    slice_kernel<<<NBLK, 512, 0, stream>>>(uu, vv, rr, bins, cursor, out);
}

// Round 19
// 64.059 us; speedup vs baseline: 6.0926x; 1.0018x over previous
//
#include <hip/hip_runtime.h>

#define NN 50000
#define NE 800000
#define D 64
#define SLICE 64                        // dst nodes per slice block
#define NBLK 782                        // ceil(NN/SLICE) = buckets
#define BCAP 1536                       // per-bucket capacity (mean 1024, >15 sigma)
#define CSTRIDE 4                       // cursor padding: 16 B
#define UVNODES 64                      // nodes per uv block (16 per wave)
#define UVBLK 782                       // ceil(NN/UVNODES) -> 3 blocks/CU residency
#define BINBLK 98                       // fat bin blocks (8192 edges each)
#define EPB 8192                        // edges per bin block
#define SCRTOT 2304                     // sorted-list capacity
#define CURWORDS (NBLK * CSTRIDE)       // 3128 dwords

typedef int i32x4 __attribute__((ext_vector_type(4)));
typedef float f32x4 __attribute__((ext_vector_type(4)));

__device__ __forceinline__ float b2f(unsigned short h) {
    unsigned int u = ((unsigned int)h) << 16;
    return __builtin_bit_cast(float, u);
}
__device__ __forceinline__ unsigned short f2bf(float f) {
    unsigned int u = __builtin_bit_cast(unsigned int, f);
    u = (u + 0x7fffu + ((u >> 16) & 1u)) >> 16;
    return (unsigned short)u;
}

// ---------------------------------------------------------------------------
// zero_cursor: replaces hipMemsetAsync for the 12.5K-dword cursor array.
// ---------------------------------------------------------------------------
__global__ __launch_bounds__(256) void zero_cursor(unsigned int* __restrict__ cursor)
{
    int i = blockIdx.x * 256 + threadIdx.x;
    if (i < CURWORDS) cursor[i] = 0u;
}

// ---------------------------------------------------------------------------
// pre_fused: blocks [0, UVBLK) = uv/res GEMMs, 64 nodes/block (16/wave) so
// the grid reaches 3-blocks/CU residency (was 1.5 -> occupancy 16%, no
// latency hiding). W staged via f32x4. Blocks [UVBLK, ..) = histogram
// binning (LDS hist -> one global atomicAdd per touched bucket -> place).
// ---------------------------------------------------------------------------
__global__ __launch_bounds__(256) void pre_fused(
    const float* __restrict__ x,
    const int* __restrict__ ei,
    const float* __restrict__ W_edge,
    const float* __restrict__ b_edge,
    const float* __restrict__ W_res,
    const float* __restrict__ b_res,
    unsigned short* __restrict__ u,
    unsigned short* __restrict__ v,
    unsigned short* __restrict__ res,
    unsigned int* __restrict__ bins,
    unsigned int* __restrict__ cursor)
{
    __shared__ float Wu[D * D];        // Wtop - Wbot   (16 KB)  | bin: hist/fill
    __shared__ float Wv[D * D];        // Wbot          (16 KB)  | bin: base
    __shared__ float Wr[D * D];        // W_res         (16 KB)
    __shared__ float xs[4][D][4];      // [wave][k][node] (4 KB)

    const int tid  = threadIdx.x;
    const int lane = tid & 63;
    const int wid  = tid >> 6;

    if (blockIdx.x < UVBLK) {
        {   // vectorized W staging: 4 f32x4 iters per matrix per thread
            const f32x4* __restrict__ We4 = (const f32x4*)W_edge;
            const f32x4* __restrict__ Wr4 = (const f32x4*)W_res;
            f32x4* __restrict__ Wu4 = (f32x4*)Wu;
            f32x4* __restrict__ Wv4 = (f32x4*)Wv;
            f32x4* __restrict__ WrL = (f32x4*)Wr;
            for (int i = tid; i < (D * D) / 4; i += 256) {
                f32x4 wt = We4[i], wb = We4[(D * D) / 4 + i];
                Wu4[i] = wt - wb;
                Wv4[i] = wb;
                WrL[i] = Wr4[i];
            }
        }

        // upfront x prefetch: 16 independent loads (clamped base, stores guarded)
        float xr[4][4];
#pragma unroll
        for (int g = 0; g < 4; ++g) {
            int n0 = blockIdx.x * UVNODES + wid * 16 + g * 4;
            int n0c = (n0 <= NN - 4) ? n0 : (NN - 4);
#pragma unroll
            for (int j = 0; j < 4; ++j)
                xr[g][j] = x[(size_t)(n0c + j) * D + lane];
        }
        __syncthreads();

        const float be = b_edge[lane];
        const float br = b_res[lane];
#pragma unroll 1
        for (int g = 0; g < 4; ++g) {
            const int n0 = blockIdx.x * UVNODES + wid * 16 + g * 4;
#pragma unroll
            for (int j = 0; j < 4; ++j)
                xs[wid][lane][j] = xr[g][j];
            float au0 = be, au1 = be, au2 = be, au3 = be;
            float av0 = 0.f, av1 = 0.f, av2 = 0.f, av3 = 0.f;
            float ar0 = br, ar1 = br, ar2 = br, ar3 = br;
#pragma unroll
            for (int k = 0; k < D; ++k) {
                f32x4 x4 = *(const f32x4*)&xs[wid][k][0];   // wave-uniform
                float wu = Wu[k * D + lane];
                float wv = Wv[k * D + lane];
                float wr = Wr[k * D + lane];
                au0 += x4[0] * wu;  av0 += x4[0] * wv;  ar0 += x4[0] * wr;
                au1 += x4[1] * wu;  av1 += x4[1] * wv;  ar1 += x4[1] * wr;
                au2 += x4[2] * wu;  av2 += x4[2] * wv;  ar2 += x4[2] * wr;
                au3 += x4[3] * wu;  av3 += x4[3] * wv;  ar3 += x4[3] * wr;
            }
            if (n0 < NN) {   // n0 % 4 == 0 and NN % 4 == 0 -> all 4 valid
                u[(size_t)(n0 + 0) * D + lane] = f2bf(au0);
                u[(size_t)(n0 + 1) * D + lane] = f2bf(au1);
                u[(size_t)(n0 + 2) * D + lane] = f2bf(au2);
                u[(size_t)(n0 + 3) * D + lane] = f2bf(au3);
                v[(size_t)(n0 + 0) * D + lane] = f2bf(av0);
                v[(size_t)(n0 + 1) * D + lane] = f2bf(av1);
                v[(size_t)(n0 + 2) * D + lane] = f2bf(av2);
                v[(size_t)(n0 + 3) * D + lane] = f2bf(av3);
                res[(size_t)(n0 + 0) * D + lane] = f2bf(ar0);
                res[(size_t)(n0 + 1) * D + lane] = f2bf(ar1);
                res[(size_t)(n0 + 2) * D + lane] = f2bf(ar2);
                res[(size_t)(n0 + 3) * D + lane] = f2bf(ar3);
            }
        }
    } else {
        // ---- histogram binning ----
        const int bb = blockIdx.x - UVBLK;
        if (bb == 0 && tid < 64)
            v[(size_t)NN * D + tid] = 0xFF80;           // sentinel row = -inf
        int* hist  = (int*)Wu;            // [NBLK]
        int* fillb = (int*)Wu + 1024;     // [NBLK]
        int* baseb = (int*)Wv;            // [NBLK]
        for (int i = tid; i < NBLK; i += 256) { hist[i] = 0; fillb[i] = 0; }
        __syncthreads();

        // phase A: LDS histogram (8 x int4 per thread, strided chunks)
#pragma unroll 1
        for (int t = 0; t < 8; ++t) {
            int e = bb * EPB + t * 1024 + tid * 4;
            if (e < NE) {
                i32x4 d4 = *(const i32x4*)(ei + NE + e);
#pragma unroll
                for (int j = 0; j < 4; ++j)
                    atomicAdd(&hist[((unsigned int)d4[j]) >> 6], 1);
            }
        }
        __syncthreads();

        // phase B: one global atomicAdd per touched bucket
        for (int b = tid; b < NBLK; b += 256) {
            int h = hist[b];
            baseb[b] = h ? (int)atomicAdd(&cursor[b * CSTRIDE], (unsigned)h) : 0;
        }
        __syncthreads();

        // phase C: place edges (re-read, L1/L2 hot)
#pragma unroll 1
        for (int t = 0; t < 8; ++t) {
            int e = bb * EPB + t * 1024 + tid * 4;
            if (e < NE) {
                i32x4 s4 = *(const i32x4*)(ei + e);
                i32x4 d4 = *(const i32x4*)(ei + NE + e);
#pragma unroll
                for (int j = 0; j < 4; ++j) {
                    unsigned int de = (unsigned int)d4[j];
                    unsigned int b  = de >> 6;
                    int pos = baseb[b] + atomicAdd(&fillb[b], 1);
                    if (pos < BCAP)
                        bins[(size_t)b * BCAP + pos] =
                            (((unsigned int)s4[j]) << 6) | (de & 63u);
                }
            }
        }
    }
}

// ---------------------------------------------------------------------------
// slice: CSR build (all 512 threads) + unroll-1 row loop:
//   m = register max over neighbor v-rows; out = relu(u+m) + res.
// ---------------------------------------------------------------------------
__global__ __launch_bounds__(512) void slice_kernel(
    const unsigned short* __restrict__ u,
    const unsigned short* __restrict__ v,
    const unsigned short* __restrict__ res,
    const unsigned int* __restrict__ bins,
    const unsigned int* __restrict__ cursor,
    float* __restrict__ out)
{
    __shared__ int sorted[SCRTOT];     // src ids, CSR by row
    __shared__ int cntL[64], ofsL[64], fillL[64];

    const int tid  = threadIdx.x;
    const int lane = tid & 63;
    const int wid  = tid >> 6;                 // 0..7
    const int base = blockIdx.x * SLICE;

    if (tid < 64) { cntL[tid] = 0; fillL[tid] = 0; }
    __syncthreads();

    unsigned int cnt = cursor[blockIdx.x * CSTRIDE];
    if (cnt > BCAP) cnt = BCAP;
    const unsigned int* __restrict__ eb = bins + (size_t)blockIdx.x * BCAP;

    // ---- histogram by dst row (all threads) ----
    for (unsigned int i0 = tid; i0 < cnt; i0 += 512)
        atomicAdd(&cntL[eb[i0] & 63u], 1);
    __syncthreads();

    // ---- exclusive prefix scan of x4-rounded counts (wave 0) ----
    if (wid == 0) {
        int a = (cntL[lane] + 3) & ~3;
        int s = a;
#pragma unroll
        for (int off = 1; off < 64; off <<= 1) {
            int t = __shfl_up(s, off);
            if (lane >= off) s += t;
        }
        ofsL[lane] = s - a;
    }
    __syncthreads();

    // ---- scatter into CSR ----
    for (unsigned int i0 = tid; i0 < cnt; i0 += 512) {
        unsigned int e = eb[i0];
        int dl = (int)(e & 63u);
        int pos = ofsL[dl] + atomicAdd(&fillL[dl], 1);
        sorted[pos] = (int)(e >> 6);
    }
    __syncthreads();

    // ---- pad lists to x4 with sentinel (+4 tail for prefetch overread) ----
    if (tid < 64) {
        int c = cntL[tid], o = ofsL[tid];
        int a = (c + 3) & ~3;
        for (int j = c; j < a; ++j) sorted[o + j] = NN;
        if (tid == 63)
            for (int t = 0; t < 4; ++t) sorted[o + a + t] = NN;
    }
    __syncthreads();

    // ---- aggregate + trivial epilogue: 8 rows per wave, lane = column ----
#pragma unroll 1
    for (int i = 0; i < 8; ++i) {
        int r = wid * 8 + i;
        int n = base + r;
        if (n >= NN) break;
        float ur = b2f(u[(size_t)n * D + lane]);
        float rr = b2f(res[(size_t)n * D + lane]);
        const int o = ofsL[r];
        const int a = (cntL[r] + 3) & ~3;
        float m = -__builtin_inff();
        i32x4 idx = *(const i32x4*)&sorted[o];          // uniform broadcast
#pragma unroll 2
        for (int j = 0; j < a; j += 4) {
            i32x4 nx = *(const i32x4*)&sorted[o + j + 4];  // prefetch
            float v0 = b2f(v[(size_t)idx[0] * D + lane]);
            float v1 = b2f(v[(size_t)idx[1] * D + lane]);
            float v2 = b2f(v[(size_t)idx[2] * D + lane]);
            float v3 = b2f(v[(size_t)idx[3] * D + lane]);
            m = fmaxf(m, fmaxf(fmaxf(v0, v1), fmaxf(v2, v3)));
            idx = nx;
        }
        float agg = fmaxf(0.f, ur + m);   // relu; empty row -> -inf -> 0
        out[(size_t)n * D + lane] = agg + rr;
    }
}

extern "C" void kernel_launch(void* const* d_in, const int* in_sizes, int n_in,
                              void* d_out, int out_size, void* d_ws, size_t ws_size,
                              hipStream_t stream) {
    const float* x      = (const float*)d_in[0];
    const int*   ei     = (const int*)d_in[1];
    const float* W_edge = (const float*)d_in[2];
    const float* b_edge = (const float*)d_in[3];
    const float* W_res  = (const float*)d_in[4];
    const float* b_res  = (const float*)d_in[5];
    float* out = (float*)d_out;

    // ws: cursor u32[CURWORDS] (reserve 64KB) | bins u32[NBLK*BCAP] (4.8MB)
    //     | u bf16 (6.4MB) | v bf16 (6.4MB + sentinel row) | res bf16 (6.4MB)
    unsigned int*   cursor = (unsigned int*)d_ws;
    unsigned int*   bins   = (unsigned int*)((char*)d_ws + (1u << 16));
    unsigned short* uu     = (unsigned short*)((char*)d_ws + (1u << 16)
                              + (size_t)NBLK * BCAP * 4);
    unsigned short* vv     = uu + (size_t)NN * D;
    unsigned short* rr     = vv + (size_t)(NN + 1) * D;   // after sentinel row

    zero_cursor<<<(CURWORDS + 255) / 256, 256, 0, stream>>>(cursor);
    pre_fused<<<UVBLK + BINBLK, 256, 0, stream>>>(x, ei, W_edge, b_edge, W_res, b_res,
                                                  uu, vv, rr, bins, cursor);
    slice_kernel<<<NBLK, 512, 0, stream>>>(uu, vv, rr, bins, cursor, out);
}